// Round 7
// baseline (270.980 us; speedup 1.0000x reference)
//
#include <hip/hip_runtime.h>

#define NN 100000
#define EE 500000
#define FIN 64
#define HH 128
#define BN_EPS 1e-5f
#define NB ((NN + 255) / 256)   // 391 scan blocks

typedef unsigned short u16;
typedef short bf16x8 __attribute__((ext_vector_type(8)));
typedef float f32x4 __attribute__((ext_vector_type(4)));

__device__ __forceinline__ u16 f2bf(float f) {
    unsigned int u = __float_as_uint(f);
    u = (u + 0x7FFFu + ((u >> 16) & 1u)) >> 16;   // round-to-nearest-even
    return (u16)u;
}
__device__ __forceinline__ float bf2f(u16 u) {
    return __uint_as_float((unsigned int)u << 16);
}

// ---------------- CSR build ----------------

__global__ __launch_bounds__(256) void hist_kernel(const int* __restrict__ dst,
                                                   int* __restrict__ deg) {
    int e = blockIdx.x * 256 + threadIdx.x;
    if (e < EE) atomicAdd(&deg[dst[e]], 1);
}

__global__ __launch_bounds__(256) void dinv_kernel(const int* __restrict__ deg,
                                                   float* __restrict__ dinv) {
    int i = blockIdx.x * 256 + threadIdx.x;
    if (i < NN) dinv[i] = rsqrtf((float)deg[i] + 1.0f);
}

__global__ __launch_bounds__(256) void scan1_kernel(const int* __restrict__ deg,
                                                    int* __restrict__ rowstart,
                                                    int* __restrict__ blksum) {
    __shared__ int s[256];
    int t = threadIdx.x;
    int i = blockIdx.x * 256 + t;
    int v = (i < NN) ? deg[i] : 0;
    s[t] = v;
    __syncthreads();
    #pragma unroll
    for (int off = 1; off < 256; off <<= 1) {
        int add = (t >= off) ? s[t - off] : 0;
        __syncthreads();
        s[t] += add;
        __syncthreads();
    }
    if (i < NN) rowstart[i] = s[t] - v;
    if (t == 255) blksum[blockIdx.x] = s[255];
}

__global__ __launch_bounds__(512) void scan2_kernel(int* __restrict__ blksum) {
    __shared__ int s[512];
    int t = threadIdx.x;
    int v = (t < NB) ? blksum[t] : 0;
    s[t] = v;
    __syncthreads();
    #pragma unroll
    for (int off = 1; off < 512; off <<= 1) {
        int add = (t >= off) ? s[t - off] : 0;
        __syncthreads();
        s[t] += add;
        __syncthreads();
    }
    if (t < NB) blksum[t] = s[t] - v;
}

__global__ __launch_bounds__(256) void scan3_kernel(int* __restrict__ rowstart,
                                                    const int* __restrict__ blksum,
                                                    int* __restrict__ cursor) {
    int i = blockIdx.x * 256 + threadIdx.x;
    if (i < NN) {
        int r = rowstart[i] + blksum[i >> 8];
        rowstart[i] = r;
        cursor[i] = r;
    }
    if (i == 0) rowstart[NN] = EE;
}

__global__ __launch_bounds__(256) void fill_kernel(const int* __restrict__ src,
                                                   const int* __restrict__ dst,
                                                   const float* __restrict__ dinv,
                                                   int* __restrict__ cursor,
                                                   int2* __restrict__ csr) {
    int e = blockIdx.x * 256 + threadIdx.x;
    if (e >= EE) return;
    int s = src[e];
    int d = dst[e];
    float nm = dinv[s] * dinv[d];
    int pos = atomicAdd(&cursor[d], 1);
    csr[pos] = make_int2(s, __float_as_int(nm));
}

// ---------------- fp32 -> bf16 convert (input features) ----------------

__global__ __launch_bounds__(256) void x2bf_kernel(const float* __restrict__ x,
                                                   u16* __restrict__ xb) {
    int i = blockIdx.x * 256 + threadIdx.x;
    if (i >= NN * FIN / 4) return;
    float4 f = ((const float4*)x)[i];
    uint2 o;
    o.x = (unsigned)f2bf(f.x) | ((unsigned)f2bf(f.y) << 16);
    o.y = (unsigned)f2bf(f.z) | ((unsigned)f2bf(f.w) << 16);
    ((uint2*)xb)[i] = o;
}

// ---------------- W [K][HH] fp32 -> Wt [HH][K] bf16 (transpose-convert) ----------------

template<int K>
__global__ __launch_bounds__(256) void wconv_kernel(const float* __restrict__ W,
                                                    u16* __restrict__ Wt) {
    int i = blockIdx.x * 256 + threadIdx.x;
    if (i >= HH * K) return;
    int n = i / K;
    int k = i - n * K;
    Wt[i] = f2bf(W[(size_t)k * HH + n]);
}

// ---------------- gather aggregation (bf16 in/out, fp32 accumulate) ----------------

__global__ __launch_bounds__(256) void agg128_kernel(const u16* __restrict__ x,
                                                     const int2* __restrict__ csr,
                                                     const int* __restrict__ rowstart,
                                                     const float* __restrict__ dinv,
                                                     u16* __restrict__ out) {
    int gid = blockIdx.x * 8 + (threadIdx.x >> 5);
    int lane = threadIdx.x & 31;
    if (gid >= NN) return;
    float sn = dinv[gid];
    sn *= sn;
    const ushort4* xp = (const ushort4*)x;   // row = 32 x ushort4
    ushort4 xv = xp[(size_t)gid * 32 + lane];
    float a0 = bf2f(xv.x) * sn, a1 = bf2f(xv.y) * sn;
    float a2 = bf2f(xv.z) * sn, a3 = bf2f(xv.w) * sn;
    int e0 = rowstart[gid], e1 = rowstart[gid + 1];
    int e = e0;
    for (; e + 4 <= e1; e += 4) {
        int2 d0 = csr[e + 0];
        int2 d1 = csr[e + 1];
        int2 d2 = csr[e + 2];
        int2 d3 = csr[e + 3];
        ushort4 s0 = xp[(size_t)d0.x * 32 + lane];
        ushort4 s1 = xp[(size_t)d1.x * 32 + lane];
        ushort4 s2 = xp[(size_t)d2.x * 32 + lane];
        ushort4 s3 = xp[(size_t)d3.x * 32 + lane];
        float w0 = __int_as_float(d0.y), w1 = __int_as_float(d1.y);
        float w2 = __int_as_float(d2.y), w3 = __int_as_float(d3.y);
        a0 += bf2f(s0.x) * w0; a1 += bf2f(s0.y) * w0; a2 += bf2f(s0.z) * w0; a3 += bf2f(s0.w) * w0;
        a0 += bf2f(s1.x) * w1; a1 += bf2f(s1.y) * w1; a2 += bf2f(s1.z) * w1; a3 += bf2f(s1.w) * w1;
        a0 += bf2f(s2.x) * w2; a1 += bf2f(s2.y) * w2; a2 += bf2f(s2.z) * w2; a3 += bf2f(s2.w) * w2;
        a0 += bf2f(s3.x) * w3; a1 += bf2f(s3.y) * w3; a2 += bf2f(s3.z) * w3; a3 += bf2f(s3.w) * w3;
    }
    for (; e < e1; e++) {
        int2 ed = csr[e];
        float w = __int_as_float(ed.y);
        ushort4 xs = xp[(size_t)ed.x * 32 + lane];
        a0 += bf2f(xs.x) * w; a1 += bf2f(xs.y) * w;
        a2 += bf2f(xs.z) * w; a3 += bf2f(xs.w) * w;
    }
    uint2 o;
    o.x = (unsigned)f2bf(a0) | ((unsigned)f2bf(a1) << 16);
    o.y = (unsigned)f2bf(a2) | ((unsigned)f2bf(a3) << 16);
    ((uint2*)out)[(size_t)gid * 32 + lane] = o;
}

__global__ __launch_bounds__(256) void agg64_kernel(const u16* __restrict__ x,
                                                    const int2* __restrict__ csr,
                                                    const int* __restrict__ rowstart,
                                                    const float* __restrict__ dinv,
                                                    u16* __restrict__ out) {
    int gid = blockIdx.x * 16 + (threadIdx.x >> 4);
    int lane = threadIdx.x & 15;
    if (gid >= NN) return;
    float sn = dinv[gid];
    sn *= sn;
    const ushort4* xp = (const ushort4*)x;   // row = 16 x ushort4
    ushort4 xv = xp[(size_t)gid * 16 + lane];
    float a0 = bf2f(xv.x) * sn, a1 = bf2f(xv.y) * sn;
    float a2 = bf2f(xv.z) * sn, a3 = bf2f(xv.w) * sn;
    int e0 = rowstart[gid], e1 = rowstart[gid + 1];
    int e = e0;
    for (; e + 4 <= e1; e += 4) {
        int2 d0 = csr[e + 0];
        int2 d1 = csr[e + 1];
        int2 d2 = csr[e + 2];
        int2 d3 = csr[e + 3];
        ushort4 s0 = xp[(size_t)d0.x * 16 + lane];
        ushort4 s1 = xp[(size_t)d1.x * 16 + lane];
        ushort4 s2 = xp[(size_t)d2.x * 16 + lane];
        ushort4 s3 = xp[(size_t)d3.x * 16 + lane];
        float w0 = __int_as_float(d0.y), w1 = __int_as_float(d1.y);
        float w2 = __int_as_float(d2.y), w3 = __int_as_float(d3.y);
        a0 += bf2f(s0.x) * w0; a1 += bf2f(s0.y) * w0; a2 += bf2f(s0.z) * w0; a3 += bf2f(s0.w) * w0;
        a0 += bf2f(s1.x) * w1; a1 += bf2f(s1.y) * w1; a2 += bf2f(s1.z) * w1; a3 += bf2f(s1.w) * w1;
        a0 += bf2f(s2.x) * w2; a1 += bf2f(s2.y) * w2; a2 += bf2f(s2.z) * w2; a3 += bf2f(s2.w) * w2;
        a0 += bf2f(s3.x) * w3; a1 += bf2f(s3.y) * w3; a2 += bf2f(s3.z) * w3; a3 += bf2f(s3.w) * w3;
    }
    for (; e < e1; e++) {
        int2 ed = csr[e];
        float w = __int_as_float(ed.y);
        ushort4 xs = xp[(size_t)ed.x * 16 + lane];
        a0 += bf2f(xs.x) * w; a1 += bf2f(xs.y) * w;
        a2 += bf2f(xs.z) * w; a3 += bf2f(xs.w) * w;
    }
    uint2 o;
    o.x = (unsigned)f2bf(a0) | ((unsigned)f2bf(a1) << 16);
    o.y = (unsigned)f2bf(a2) | ((unsigned)f2bf(a3) << 16);
    ((uint2*)out)[(size_t)gid * 16 + lane] = o;
}

// ---------------- MFMA GEMM + bias + BN(eval) + ReLU (+ residual) ----------------
// No LDS, no barriers. B-fragments loaded from pre-converted Wt[HH][K] bf16 (L2-hot).
// Block = 256 thr = 4 waves; each wave owns 16 rows (BM=64). grid = ceil(N/64).
// FUSE_Z: instead of storing C, compute z[row] = dot(C_row, W4) via 16-lane reduce.

template<int K, bool FUSE_Z>
__global__ __launch_bounds__(256) void gemm_bn_relu(const u16* __restrict__ A,
                                                    const u16* __restrict__ Wt,
                                                    const float* __restrict__ bias,
                                                    const float* __restrict__ g,
                                                    const float* __restrict__ be,
                                                    const float* __restrict__ m,
                                                    const float* __restrict__ v,
                                                    const u16* __restrict__ res,
                                                    u16* __restrict__ out,
                                                    const float* __restrict__ W4,
                                                    float* __restrict__ z) {
    int tid = threadIdx.x;
    int wave = tid >> 6;
    int lane = tid & 63;
    int lrow = lane & 15;
    int kgrp = lane >> 4;

    int r0 = blockIdx.x * 64 + wave * 16;
    int arow = r0 + lrow;
    if (arow >= NN) arow = NN - 1;

    f32x4 acc[8];
    #pragma unroll
    for (int ct = 0; ct < 8; ct++) acc[ct] = (f32x4){0.f, 0.f, 0.f, 0.f};

    #pragma unroll
    for (int kc = 0; kc < K / 32; kc++) {
        bf16x8 afr = *(const bf16x8*)&A[(size_t)arow * K + kc * 32 + kgrp * 8];
        bf16x8 bfr[8];
        #pragma unroll
        for (int ct = 0; ct < 8; ct++)
            bfr[ct] = *(const bf16x8*)&Wt[(size_t)(ct * 16 + lrow) * K + kc * 32 + kgrp * 8];
        #pragma unroll
        for (int ct = 0; ct < 8; ct++)
            acc[ct] = __builtin_amdgcn_mfma_f32_16x16x32_bf16(afr, bfr[ct], acc[ct], 0, 0, 0);
    }

    // BN scale/shift for this lane's 8 columns (col = ct*16 + lrow)
    float sc[8], sh[8];
    #pragma unroll
    for (int ct = 0; ct < 8; ct++) {
        int col = ct * 16 + lrow;
        float s = g[col] * rsqrtf(v[col] + BN_EPS);
        sc[ct] = s;
        sh[ct] = (bias[col] - m[col]) * s + be[col];
    }

    int rbase = kgrp * 4;   // C layout: row = r0 + rbase + r, col = ct*16 + lrow
    if constexpr (!FUSE_Z) {
        #pragma unroll
        for (int r = 0; r < 4; r++) {
            int row = r0 + rbase + r;
            if (row >= NN) continue;
            #pragma unroll
            for (int ct = 0; ct < 8; ct++) {
                float val = acc[ct][r] * sc[ct] + sh[ct];
                val = fmaxf(val, 0.0f);
                if (res) val += bf2f(res[(size_t)row * HH + ct * 16 + lrow]);
                out[(size_t)row * HH + ct * 16 + lrow] = f2bf(val);
            }
        }
    } else {
        // layer-3 + layer-4 GEMV fusion: z[row] = sum_col relu(bn(C))+res) * W4[col]
        float w4[8];
        #pragma unroll
        for (int ct = 0; ct < 8; ct++) w4[ct] = W4[ct * 16 + lrow];
        #pragma unroll
        for (int r = 0; r < 4; r++) {
            int row = r0 + rbase + r;
            float part = 0.0f;
            #pragma unroll
            for (int ct = 0; ct < 8; ct++) {
                float val = acc[ct][r] * sc[ct] + sh[ct];
                val = fmaxf(val, 0.0f);
                val += bf2f(res[(size_t)row * HH + ct * 16 + lrow]);
                part += val * w4[ct];
            }
            #pragma unroll
            for (int off = 1; off < 16; off <<= 1)
                part += __shfl_xor(part, off, 16);
            if (lrow == 0 && row < NN) z[row] = part;
        }
    }
}

// ---------------- final: out[i] = b4 + z[i]*dinv^2 + sum z[src]*w ----------------

__global__ __launch_bounds__(256) void final_kernel(const float* __restrict__ z,
                                                    const int2* __restrict__ csr,
                                                    const int* __restrict__ rowstart,
                                                    const float* __restrict__ dinv,
                                                    const float* __restrict__ b4,
                                                    float* __restrict__ out) {
    int i = blockIdx.x * 256 + threadIdx.x;
    if (i >= NN) return;
    float acc = z[i] * dinv[i] * dinv[i] + b4[0];
    int e0 = rowstart[i], e1 = rowstart[i + 1];
    int e = e0;
    for (; e + 4 <= e1; e += 4) {
        int2 d0 = csr[e + 0];
        int2 d1 = csr[e + 1];
        int2 d2 = csr[e + 2];
        int2 d3 = csr[e + 3];
        float z0 = z[d0.x], z1 = z[d1.x], z2 = z[d2.x], z3 = z[d3.x];
        acc += z0 * __int_as_float(d0.y) + z1 * __int_as_float(d1.y)
             + z2 * __int_as_float(d2.y) + z3 * __int_as_float(d3.y);
    }
    for (; e < e1; e++) {
        int2 ed = csr[e];
        acc += z[ed.x] * __int_as_float(ed.y);
    }
    out[i] = acc;
}

// ---------------- launch ----------------

extern "C" void kernel_launch(void* const* d_in, const int* in_sizes, int n_in,
                              void* d_out, int out_size, void* d_ws, size_t ws_size,
                              hipStream_t stream) {
    const float* x   = (const float*)d_in[0];
    const int*   ei  = (const int*)d_in[1];
    const int*   src = ei;
    const int*   dst = ei + EE;
    const float* W1 = (const float*)d_in[2];
    const float* b1 = (const float*)d_in[3];
    const float* g1 = (const float*)d_in[4];
    const float* be1 = (const float*)d_in[5];
    const float* m1 = (const float*)d_in[6];
    const float* v1 = (const float*)d_in[7];
    const float* W2 = (const float*)d_in[8];
    const float* b2 = (const float*)d_in[9];
    const float* g2 = (const float*)d_in[10];
    const float* be2 = (const float*)d_in[11];
    const float* m2 = (const float*)d_in[12];
    const float* v2 = (const float*)d_in[13];
    const float* W3 = (const float*)d_in[14];
    const float* b3 = (const float*)d_in[15];
    const float* g3 = (const float*)d_in[16];
    const float* be3 = (const float*)d_in[17];
    const float* m3 = (const float*)d_in[18];
    const float* v3 = (const float*)d_in[19];
    const float* W4 = (const float*)d_in[20];
    const float* b4 = (const float*)d_in[21];

    char* wp = (char*)d_ws;
    int*   deg      = (int*)wp;                      wp += (size_t)NN * 4;
    int*   blksum   = (int*)wp;                      wp += 512 * 4;
    int*   rowstart = (int*)wp;                      wp += (size_t)(NN + 1) * 4;
    int*   cursor   = (int*)wp;                      wp += (size_t)NN * 4;
    float* dinv     = (float*)wp;                    wp += (size_t)NN * 4;
    int2*  csr      = (int2*)wp;                     wp += (size_t)EE * 8;
    float* z        = (float*)wp;                    wp += (size_t)NN * 4;
    u16*   wt1      = (u16*)wp;                      wp += (size_t)HH * FIN * 2;
    u16*   wt2      = (u16*)wp;                      wp += (size_t)HH * HH * 2;
    u16*   wt3      = (u16*)wp;                      wp += (size_t)HH * HH * 2;
    u16*   xb       = (u16*)wp;                      wp += (size_t)NN * FIN * 2;
    u16*   x1       = (u16*)wp;                      wp += (size_t)NN * HH * 2;
    u16*   bufA     = (u16*)wp;                      wp += (size_t)NN * HH * 2;
    u16*   bufB     = (u16*)wp;                      wp += (size_t)NN * HH * 2;

    float* outp = (float*)d_out;

    // ---- CSR build + weight/feature conversions
    hipMemsetAsync(deg, 0, (size_t)NN * 4, stream);
    hist_kernel<<<(EE + 255) / 256, 256, 0, stream>>>(dst, deg);
    x2bf_kernel<<<(NN * FIN / 4 + 255) / 256, 256, 0, stream>>>(x, xb);
    wconv_kernel<FIN><<<(HH * FIN + 255) / 256, 256, 0, stream>>>(W1, wt1);
    wconv_kernel<HH><<<(HH * HH + 255) / 256, 256, 0, stream>>>(W2, wt2);
    wconv_kernel<HH><<<(HH * HH + 255) / 256, 256, 0, stream>>>(W3, wt3);
    dinv_kernel<<<(NN + 255) / 256, 256, 0, stream>>>(deg, dinv);
    scan1_kernel<<<NB, 256, 0, stream>>>(deg, rowstart, blksum);
    scan2_kernel<<<1, 512, 0, stream>>>(blksum);
    scan3_kernel<<<NB, 256, 0, stream>>>(rowstart, blksum, cursor);
    fill_kernel<<<(EE + 255) / 256, 256, 0, stream>>>(src, dst, dinv, cursor, csr);

    // ---- layer 1: aggregate xb (64 feat), then GEMM 64->128 + BN + ReLU
    agg64_kernel<<<(NN + 15) / 16, 256, 0, stream>>>(xb, csr, rowstart, dinv, bufA);
    gemm_bn_relu<FIN, false><<<(NN + 63) / 64, 256, 0, stream>>>(
        bufA, wt1, b1, g1, be1, m1, v1, nullptr, x1, nullptr, nullptr);

    // ---- layer 2
    agg128_kernel<<<(NN + 7) / 8, 256, 0, stream>>>(x1, csr, rowstart, dinv, bufA);
    gemm_bn_relu<HH, false><<<(NN + 63) / 64, 256, 0, stream>>>(
        bufA, wt2, b2, g2, be2, m2, v2, nullptr, bufB, nullptr, nullptr);

    // ---- layer 3 (+ residual x1) fused with layer-4 GEMV -> z
    agg128_kernel<<<(NN + 7) / 8, 256, 0, stream>>>(bufB, csr, rowstart, dinv, bufA);
    gemm_bn_relu<HH, true><<<(NN + 63) / 64, 256, 0, stream>>>(
        bufA, wt3, b3, g3, be3, m3, v3, x1, nullptr, W4, z);

    // ---- final aggregation of scalars
    final_kernel<<<(NN + 255) / 256, 256, 0, stream>>>(z, csr, rowstart, dinv, b4, outp);
}